// Round 2
// baseline (170.967 us; speedup 1.0000x reference)
//
#include <hip/hip_runtime.h>
#include <hip/hip_bf16.h>

typedef unsigned short u16;
typedef unsigned int u32;
typedef __bf16 bf16x8 __attribute__((ext_vector_type(8)));
typedef float f32x4 __attribute__((ext_vector_type(4)));

#define NB 2
#define NL 2048
#define NDM 1024
#define NH 16
#define NHD 64
#define NRH 16
#define NCOL 2304  // 1024 q | 1024 k | 256 v

#define AS1(p) ((const __attribute__((address_space(1))) void*)(p))
#define AS3(p) ((__attribute__((address_space(3))) void*)(p))

__device__ __forceinline__ u16 f2bf(float f) {
  u32 u = __builtin_bit_cast(u32, f);
  u32 r = (u + 0x7fffu + ((u >> 16) & 1u)) >> 16;
  return (u16)r;
}
__device__ __forceinline__ float bf2f(u16 b) {
  return __builtin_bit_cast(float, (u32)b << 16);
}

// ---------------- prep: effective weights  Wall[2304][1024] bf16 ----------------
// rows 0..1023: (U@Wq per head), 1024..2047: (U@Wk per head), 2048..2303: Wv
__global__ void k_prep_weff(const float* __restrict__ Wq, const float* __restrict__ Wk,
                            const float* __restrict__ Wv, const float* __restrict__ U,
                            u16* __restrict__ Wall) {
  int idx = blockIdx.x * 256 + threadIdx.x;  // NCOL*1024
  int col = idx & 1023;
  int row = idx >> 10;
  float acc;
  if (row < 2048) {
    const float* W = (row < 1024) ? Wq : Wk;
    int rr = row & 1023;
    int h = rr >> 6, d = rr & 63;
    const float* Uh = U + (h * NHD + d) * NRH;
    const float* Wr = W + (size_t)(h * NRH) * NDM + col;
    acc = 0.f;
#pragma unroll
    for (int r = 0; r < 16; ++r) acc += Uh[r] * Wr[(size_t)r * NDM];
  } else {
    acc = Wv[(size_t)(row - 2048) * NDM + col];
  }
  Wall[idx] = f2bf(acc);
}

// ---------------- cast x -> bf16 ----------------
__global__ void k_cast_x(const float* __restrict__ x, u16* __restrict__ xb) {
  int i = blockIdx.x * 256 + threadIdx.x;  // over 2M, 2 elems each
  float2 v = *(const float2*)(x + (size_t)i * 2);
  ushort2 o;
  o.x = f2bf(v.x);
  o.y = f2bf(v.y);
  *(ushort2*)(xb + (size_t)i * 2) = o;
}

// ---------------- rope cos/sin table [L][32] ----------------
__global__ void k_rope_tab(float* __restrict__ ctab, float* __restrict__ stab) {
  int i = blockIdx.x * 256 + threadIdx.x;
  if (i >= NL * 32) return;
  int l = i >> 5, j = i & 31;
  float theta = 1.0f / powf(10000.0f, (float)j * (1.0f / 32.0f));
  float ang = (float)l * theta;
  ctab[i] = cosf(ang);
  stab[i] = sinf(ang);
}

// ---------------- GEMM: pre[4096][2304] = xb[4096][1024] @ Wall^T ----------------
__global__ __launch_bounds__(256) void k_gemm(const u16* __restrict__ A,
                                              const u16* __restrict__ Bm,
                                              u16* __restrict__ C) {
  __shared__ char lds[32768];  // A tile 16KB | B tile 16KB, XOR-swizzled
  const int tid = threadIdx.x;
  const int wave = tid >> 6, lane = tid & 63;
  const int bm = blockIdx.x, bn = blockIdx.y;
  const int wr = wave >> 1, wc = wave & 1;
  const char* Ag = (const char*)(A + (size_t)bm * 128 * NDM);
  const char* Bg = (const char*)(Bm + (size_t)bn * 128 * NDM);
  f32x4 acc[4][4] = {};
  for (int kt = 0; kt < 16; ++kt) {
    __syncthreads();
#pragma unroll
    for (int i = 0; i < 4; ++i) {
      int off = wave * 4096 + i * 1024 + lane * 16;
      int src = off ^ ((off >> 3) & 0x70);  // inverse-swizzled source (rule #21)
      int ga = (src >> 7) * 2048 + kt * 128 + (src & 127);
      __builtin_amdgcn_global_load_lds(AS1(Ag + ga), AS3(lds + wave * 4096 + i * 1024), 16, 0, 0);
      __builtin_amdgcn_global_load_lds(AS1(Bg + ga), AS3(lds + 16384 + wave * 4096 + i * 1024), 16, 0, 0);
    }
    __syncthreads();
#pragma unroll
    for (int kk = 0; kk < 2; ++kk) {
      bf16x8 af[4], bfr[4];
#pragma unroll
      for (int m = 0; m < 4; ++m) {
        int row = wr * 64 + m * 16 + (lane & 15);
        int byte = row * 128 + kk * 64 + ((lane >> 4) << 4);
        af[m] = *(const bf16x8*)(lds + (byte ^ ((row & 7) << 4)));
      }
#pragma unroll
      for (int n = 0; n < 4; ++n) {
        int row = wc * 64 + n * 16 + (lane & 15);
        int byte = row * 128 + kk * 64 + ((lane >> 4) << 4);
        bfr[n] = *(const bf16x8*)(lds + 16384 + (byte ^ ((row & 7) << 4)));
      }
#pragma unroll
      for (int m = 0; m < 4; ++m)
#pragma unroll
        for (int n = 0; n < 4; ++n)
          acc[m][n] = __builtin_amdgcn_mfma_f32_16x16x32_bf16(af[m], bfr[n], acc[m][n], 0, 0, 0);
    }
  }
  const int r0 = bm * 128 + wr * 64, c0 = bn * 128 + wc * 64;
#pragma unroll
  for (int m = 0; m < 4; ++m)
#pragma unroll
    for (int n = 0; n < 4; ++n)
#pragma unroll
      for (int r = 0; r < 4; ++r) {
        int row = r0 + m * 16 + ((lane >> 4) << 2) + r;
        int col = c0 + n * 16 + (lane & 15);
        C[(size_t)row * NCOL + col] = f2bf(acc[m][n][r]);
      }
}

// ---------------- rope + transpose q,k -> [b][h][l][64] bf16 ----------------
__global__ void k_rope(const u16* __restrict__ pre, const float* __restrict__ ctab,
                       const float* __restrict__ stab, u16* __restrict__ qt,
                       u16* __restrict__ kt) {
  int i = blockIdx.x * 256 + threadIdx.x;  // B*L*H*32
  int j = i & 31, hh = (i >> 5) & 15, l = (i >> 9) & 2047, b = i >> 20;
  float c = ctab[l * 32 + j], s = stab[l * 32 + j];
  const u16* prow = pre + (size_t)(b * NL + l) * NCOL;
  size_t oidx = ((size_t)((b * NH + hh) * NL + l)) * 64 + 2 * j;
  u16 a0 = prow[hh * 64 + 2 * j], a1 = prow[hh * 64 + 2 * j + 1];
  float x0 = bf2f(a0), x1 = bf2f(a1);
  qt[oidx] = f2bf(x0 * c - x1 * s);
  qt[oidx + 1] = f2bf(x0 * s + x1 * c);
  u16 b0 = prow[1024 + hh * 64 + 2 * j], b1 = prow[1024 + hh * 64 + 2 * j + 1];
  x0 = bf2f(b0);
  x1 = bf2f(b1);
  kt[oidx] = f2bf(x0 * c - x1 * s);
  kt[oidx + 1] = f2bf(x0 * s + x1 * c);
}

// ---------------- transpose v_low -> vT [b][h][r][L] bf16 ----------------
__global__ void k_vt(const u16* __restrict__ pre, u16* __restrict__ vT) {
  int i = blockIdx.x * 256 + threadIdx.x;  // B*H*16*L
  int l = i & 2047, r = (i >> 11) & 15, h = (i >> 15) & 15, b = i >> 19;
  vT[i] = pre[(size_t)(b * NL + l) * NCOL + 2048 + h * NRH + r];
}

// ---------------- flash attention ----------------
// block: one (b,h,qtile of 64 rows). 4 waves x 16 q-rows. Writes Oattn[b][h][l][16] fp32.
__global__ __launch_bounds__(256) void k_attn(const u16* __restrict__ qt,
                                              const u16* __restrict__ ktp,
                                              const u16* __restrict__ vT,
                                              const int* __restrict__ mask,
                                              float* __restrict__ Oattn) {
  __shared__ char lds[8192 + 2048 + 4 * 2048 + 256];  // K | V^T | P(per-wave) | maskbias
  const int tid = threadIdx.x, wave = tid >> 6, lane = tid & 63;
  const int blk = blockIdx.x;
  const int qtile = blk & 31, h = (blk >> 5) & 15, b = blk >> 9;
  const size_t bh = (size_t)(b * NH + h);
  const u16* Q = qt + (bh * NL + qtile * 64) * 64;
  const u16* K = ktp + bh * NL * 64;
  const u16* Vt = vT + bh * NRH * NL;
  char* Klds = lds;
  char* Vlds = lds + 8192;
  char* Plds = lds + 10240 + wave * 2048;
  float* mb = (float*)(lds + 18432);

  const int qr = wave * 16 + (lane & 15);
  bf16x8 qf0 = *(const bf16x8*)(Q + qr * 64 + ((lane >> 4) << 3));
  bf16x8 qf1 = *(const bf16x8*)(Q + qr * 64 + 32 + ((lane >> 4) << 3));

  f32x4 o = {0.f, 0.f, 0.f, 0.f};
  float M0 = -1e30f, M1 = -1e30f, M2 = -1e30f, M3 = -1e30f;
  float Ls0 = 0.f, Ls1 = 0.f, Ls2 = 0.f, Ls3 = 0.f;

  for (int t = 0; t < 32; ++t) {
    __syncthreads();
    // stage K tile 64x64 bf16 (contiguous 8KB) via global_load_lds, swizzled source
    const char* Kg = (const char*)(K + (size_t)t * 64 * 64);
#pragma unroll
    for (int i = 0; i < 2; ++i) {
      int off = wave * 2048 + i * 1024 + lane * 16;
      int src = off ^ ((off >> 3) & 0x70);
      __builtin_amdgcn_global_load_lds(AS1(Kg + src), AS3(Klds + wave * 2048 + i * 1024), 16, 0, 0);
    }
    // stage V^T tile 16x64 bf16 (2KB), reg-staged with swizzled ds_write
    if (tid < 128) {
      int rr = tid >> 3, o16 = (tid & 7) << 4;
      int4 v = *(const int4*)((const char*)(Vt + (size_t)rr * NL + t * 64) + o16);
      int dst = rr * 128 + o16;
      *(int4*)(Vlds + (dst ^ ((rr & 7) << 4))) = v;
    }
    if (tid < 64) mb[tid] = mask[b * NL + t * 64 + tid] ? 0.f : -1e30f;
    __syncthreads();

    // S = Q K^T * 0.125 + bias : 4 key-subtiles of 16
    f32x4 s0, s1, s2, s3;
#pragma unroll
    for (int n = 0; n < 4; ++n) {
      const int key = n * 16 + (lane & 15);
      const int base = key * 128 + ((lane >> 4) << 4);
      const int swz = (key & 7) << 4;
      bf16x8 kf0 = *(const bf16x8*)(Klds + (base ^ swz));
      bf16x8 kf1 = *(const bf16x8*)(Klds + ((base + 64) ^ swz));
      f32x4 z = {0.f, 0.f, 0.f, 0.f};
      z = __builtin_amdgcn_mfma_f32_16x16x32_bf16(qf0, kf0, z, 0, 0, 0);
      z = __builtin_amdgcn_mfma_f32_16x16x32_bf16(qf1, kf1, z, 0, 0, 0);
      float bias = mb[key];
      f32x4 sv;
#pragma unroll
      for (int r = 0; r < 4; ++r) sv[r] = z[r] * 0.125f + bias;
      if (n == 0) s0 = sv;
      else if (n == 1) s1 = sv;
      else if (n == 2) s2 = sv;
      else s3 = sv;
    }

    // tile row-max (rows live across 16-lane groups: reduce over lanes xor 1..8)
    float mt0 = fmaxf(fmaxf(s0[0], s1[0]), fmaxf(s2[0], s3[0]));
    float mt1 = fmaxf(fmaxf(s0[1], s1[1]), fmaxf(s2[1], s3[1]));
    float mt2 = fmaxf(fmaxf(s0[2], s1[2]), fmaxf(s2[2], s3[2]));
    float mt3 = fmaxf(fmaxf(s0[3], s1[3]), fmaxf(s2[3], s3[3]));
#pragma unroll
    for (int d = 1; d < 16; d <<= 1) {
      mt0 = fmaxf(mt0, __shfl_xor(mt0, d));
      mt1 = fmaxf(mt1, __shfl_xor(mt1, d));
      mt2 = fmaxf(mt2, __shfl_xor(mt2, d));
      mt3 = fmaxf(mt3, __shfl_xor(mt3, d));
    }
    float Mn0 = fmaxf(M0, mt0), Mn1 = fmaxf(M1, mt1);
    float Mn2 = fmaxf(M2, mt2), Mn3 = fmaxf(M3, mt3);
    float e0 = __expf(M0 - Mn0), e1 = __expf(M1 - Mn1);
    float e2 = __expf(M2 - Mn2), e3 = __expf(M3 - Mn3);
    M0 = Mn0; M1 = Mn1; M2 = Mn2; M3 = Mn3;

    float rs0 = 0.f, rs1 = 0.f, rs2 = 0.f, rs3 = 0.f;
#define PROC(sv)                          \
  sv[0] = __expf(sv[0] - M0); rs0 += sv[0]; \
  sv[1] = __expf(sv[1] - M1); rs1 += sv[1]; \
  sv[2] = __expf(sv[2] - M2); rs2 += sv[2]; \
  sv[3] = __expf(sv[3] - M3); rs3 += sv[3];
    PROC(s0) PROC(s1) PROC(s2) PROC(s3)
#undef PROC
#pragma unroll
    for (int d = 1; d < 16; d <<= 1) {
      rs0 += __shfl_xor(rs0, d);
      rs1 += __shfl_xor(rs1, d);
      rs2 += __shfl_xor(rs2, d);
      rs3 += __shfl_xor(rs3, d);
    }
    Ls0 = Ls0 * e0 + rs0; Ls1 = Ls1 * e1 + rs1;
    Ls2 = Ls2 * e2 + rs2; Ls3 = Ls3 * e3 + rs3;
    o[0] *= e0; o[1] *= e1; o[2] *= e2; o[3] *= e3;

    // write P (16x64 bf16, swizzled) to per-wave LDS
    const int prow = ((lane >> 4) << 2);
#define PW(sv, n)                                                     \
  {                                                                   \
    _Pragma("unroll") for (int r = 0; r < 4; ++r) {                   \
      int row = prow + r;                                             \
      int byteo = row * 128 + (n * 16 + (lane & 15)) * 2;             \
      *(u16*)(Plds + (byteo ^ ((row & 7) << 4))) = f2bf(sv[r]);       \
    }                                                                 \
  }
    PW(s0, 0) PW(s1, 1) PW(s2, 2) PW(s3, 3)
#undef PW

    // PV: o += P @ Vlow  (K-dim = 64 keys as 2 mfma)
#pragma unroll
    for (int c = 0; c < 2; ++c) {
      int row = lane & 15;
      int pb = row * 128 + c * 64 + ((lane >> 4) << 4);
      int sw = (row & 7) << 4;
      bf16x8 pfr = *(const bf16x8*)(Plds + (pb ^ sw));
      bf16x8 vfr = *(const bf16x8*)(Vlds + (pb ^ sw));
      o = __builtin_amdgcn_mfma_f32_16x16x32_bf16(pfr, vfr, o, 0, 0, 0);
    }
  }

  float i0 = 1.f / Ls0, i1 = 1.f / Ls1, i2 = 1.f / Ls2, i3 = 1.f / Ls3;
  o[0] *= i0; o[1] *= i1; o[2] *= i2; o[3] *= i3;
  const int qrow0 = qtile * 64 + wave * 16 + ((lane >> 4) << 2);
  float* Ob = Oattn + (bh * NL + qrow0) * NRH + (lane & 15);
  Ob[0] = o[0]; Ob[16] = o[1]; Ob[32] = o[2]; Ob[48] = o[3];
}

// ---------------- final projection: out[b][l][h*64+d] = sum_r Oattn*V ----------------
__global__ void k_proj(const float* __restrict__ Oattn, const float* __restrict__ V,
                       float* __restrict__ out) {
  int bl = blockIdx.x;  // B*L
  int b = bl >> 11, l = bl & 2047;
  __shared__ float sO[256];  // [h][r]
  int tid = threadIdx.x;
  sO[tid] = Oattn[((size_t)(b * NH + (tid >> 4)) * NL + l) * NRH + (tid & 15)];
  __syncthreads();
#pragma unroll
  for (int p = 0; p < 4; ++p) {
    int h = (tid >> 6) + p * 4;
    int d = tid & 63;
    float acc = 0.f;
    const float* Vh = V + (size_t)(h * NRH) * NHD + d;
    const float* Oh = sO + h * NRH;
#pragma unroll
    for (int r = 0; r < 16; ++r) acc += Oh[r] * Vh[(size_t)r * NHD];
    out[(size_t)bl * NDM + h * NHD + d] = acc;
  }
}

extern "C" void kernel_launch(void* const* d_in, const int* in_sizes, int n_in,
                              void* d_out, int out_size, void* d_ws, size_t ws_size,
                              hipStream_t stream) {
  (void)in_sizes; (void)n_in; (void)out_size; (void)ws_size;
  const float* x  = (const float*)d_in[0];
  const float* Wq = (const float*)d_in[1];
  const float* Wk = (const float*)d_in[2];
  const float* Wv = (const float*)d_in[3];
  const float* U  = (const float*)d_in[4];
  const float* Vm = (const float*)d_in[5];
  const int* mask = (const int*)d_in[6];
  float* out = (float*)d_out;
  char* ws = (char*)d_ws;

  u16* Wall   = (u16*)(ws);               // 4,718,592 B
  u16* xb     = (u16*)(ws + 4718592);     // 8,388,608 B
  u16* pre    = (u16*)(ws + 13107200);    // 18,874,368 B
  u16* qt     = (u16*)(ws + 31981568);    // 8,388,608 B
  u16* ktb    = (u16*)(ws + 40370176);    // 8,388,608 B
  u16* vT     = (u16*)(ws + 48758784);    // 2,097,152 B
  float* ctab = (float*)(ws + 50855936);  // 262,144 B
  float* stab = (float*)(ws + 51118080);  // 262,144 B
  float* Oattn = (float*)(ws + 4718592);  // reuse xb region (dead after GEMM)

  k_prep_weff<<<dim3(9216), dim3(256), 0, stream>>>(Wq, Wk, Wv, U, Wall);
  k_cast_x<<<dim3(8192), dim3(256), 0, stream>>>(x, xb);
  k_rope_tab<<<dim3(256), dim3(256), 0, stream>>>(ctab, stab);
  k_gemm<<<dim3(32, 18), dim3(256), 0, stream>>>(xb, Wall, pre);
  k_rope<<<dim3(8192), dim3(256), 0, stream>>>(pre, ctab, stab, qt, ktb);
  k_vt<<<dim3(4096), dim3(256), 0, stream>>>(pre, vT);
  k_attn<<<dim3(1024), dim3(256), 0, stream>>>(qt, ktb, vT, mask, Oattn);
  k_proj<<<dim3(4096), dim3(256), 0, stream>>>(Oattn, Vm, out);
}

// Round 4
// 153.160 us; speedup vs baseline: 1.1163x; 1.1163x over previous
//
#include <hip/hip_runtime.h>
#include <hip/hip_bf16.h>

typedef unsigned short u16;
typedef unsigned int u32;
typedef __bf16 bf16x8 __attribute__((ext_vector_type(8)));
typedef float f32x4 __attribute__((ext_vector_type(4)));

#define NB 2
#define NL 2048
#define NDM 1024
#define NH 16
#define NHD 64
#define NRH 16
#define NCOL 2304  // 1024 q | 1024 k | 256 v

// 0.125 * log2(e): folded into q at RoPE time so attn works in exp2 domain
#define QSCL 0.18033688011112042f

#define AS1(p) ((const __attribute__((address_space(1))) void*)(p))
#define AS3(p) ((__attribute__((address_space(3))) void*)(p))

__device__ __forceinline__ u16 f2bf(float f) {
  u32 u = __builtin_bit_cast(u32, f);
  u32 r = (u + 0x7fffu + ((u >> 16) & 1u)) >> 16;
  return (u16)r;
}
__device__ __forceinline__ float bf2f(u16 b) {
  return __builtin_bit_cast(float, (u32)b << 16);
}

// ---------------- prep: effective weights  Wall[2304][1024] bf16 ----------------
__global__ void k_prep_weff(const float* __restrict__ Wq, const float* __restrict__ Wk,
                            const float* __restrict__ Wv, const float* __restrict__ U,
                            u16* __restrict__ Wall) {
  int idx = blockIdx.x * 256 + threadIdx.x;  // NCOL*1024
  int col = idx & 1023;
  int row = idx >> 10;
  float acc;
  if (row < 2048) {
    const float* W = (row < 1024) ? Wq : Wk;
    int rr = row & 1023;
    int h = rr >> 6, d = rr & 63;
    const float* Uh = U + (h * NHD + d) * NRH;
    const float* Wr = W + (size_t)(h * NRH) * NDM + col;
    acc = 0.f;
#pragma unroll
    for (int r = 0; r < 16; ++r) acc += Uh[r] * Wr[(size_t)r * NDM];
  } else {
    acc = Wv[(size_t)(row - 2048) * NDM + col];
  }
  Wall[idx] = f2bf(acc);
}

// ---------------- cast x -> bf16 ----------------
__global__ void k_cast_x(const float* __restrict__ x, u16* __restrict__ xb) {
  int i = blockIdx.x * 256 + threadIdx.x;
  float2 v = *(const float2*)(x + (size_t)i * 2);
  ushort2 o;
  o.x = f2bf(v.x);
  o.y = f2bf(v.y);
  *(ushort2*)(xb + (size_t)i * 2) = o;
}

// ---------------- rope cos/sin table [L][32] ----------------
__global__ void k_rope_tab(float* __restrict__ ctab, float* __restrict__ stab) {
  int i = blockIdx.x * 256 + threadIdx.x;
  if (i >= NL * 32) return;
  int l = i >> 5, j = i & 31;
  float theta = 1.0f / powf(10000.0f, (float)j * (1.0f / 32.0f));
  float ang = (float)l * theta;
  ctab[i] = cosf(ang);
  stab[i] = sinf(ang);
}

// ---------------- mask -> float bias (0 / -1e30) ----------------
__global__ void k_fbias(const int* __restrict__ mask, float* __restrict__ fb) {
  int i = blockIdx.x * 256 + threadIdx.x;  // B*L = 4096
  fb[i] = mask[i] ? 0.f : -1e30f;
}

// ---------------- GEMM: pre[4096][2304] = xb[4096][1024] @ Wall^T ----------------
__global__ __launch_bounds__(256) void k_gemm(const u16* __restrict__ A,
                                              const u16* __restrict__ Bm,
                                              u16* __restrict__ C) {
  __shared__ char lds[32768];
  const int tid = threadIdx.x;
  const int wave = tid >> 6, lane = tid & 63;
  const int bm = blockIdx.x, bn = blockIdx.y;
  const int wr = wave >> 1, wc = wave & 1;
  const char* Ag = (const char*)(A + (size_t)bm * 128 * NDM);
  const char* Bg = (const char*)(Bm + (size_t)bn * 128 * NDM);
  f32x4 acc[4][4] = {};
  for (int kt = 0; kt < 16; ++kt) {
    __syncthreads();
#pragma unroll
    for (int i = 0; i < 4; ++i) {
      int off = wave * 4096 + i * 1024 + lane * 16;
      int src = off ^ ((off >> 3) & 0x70);
      int ga = (src >> 7) * 2048 + kt * 128 + (src & 127);
      __builtin_amdgcn_global_load_lds(AS1(Ag + ga), AS3(lds + wave * 4096 + i * 1024), 16, 0, 0);
      __builtin_amdgcn_global_load_lds(AS1(Bg + ga), AS3(lds + 16384 + wave * 4096 + i * 1024), 16, 0, 0);
    }
    __syncthreads();
#pragma unroll
    for (int kk = 0; kk < 2; ++kk) {
      bf16x8 af[4], bfr[4];
#pragma unroll
      for (int m = 0; m < 4; ++m) {
        int row = wr * 64 + m * 16 + (lane & 15);
        int byte = row * 128 + kk * 64 + ((lane >> 4) << 4);
        af[m] = *(const bf16x8*)(lds + (byte ^ ((row & 7) << 4)));
      }
#pragma unroll
      for (int n = 0; n < 4; ++n) {
        int row = wc * 64 + n * 16 + (lane & 15);
        int byte = row * 128 + kk * 64 + ((lane >> 4) << 4);
        bfr[n] = *(const bf16x8*)(lds + 16384 + (byte ^ ((row & 7) << 4)));
      }
#pragma unroll
      for (int m = 0; m < 4; ++m)
#pragma unroll
        for (int n = 0; n < 4; ++n)
          acc[m][n] = __builtin_amdgcn_mfma_f32_16x16x32_bf16(af[m], bfr[n], acc[m][n], 0, 0, 0);
    }
  }
  const int r0 = bm * 128 + wr * 64, c0 = bn * 128 + wc * 64;
#pragma unroll
  for (int m = 0; m < 4; ++m)
#pragma unroll
    for (int n = 0; n < 4; ++n)
#pragma unroll
      for (int r = 0; r < 4; ++r) {
        int row = r0 + m * 16 + ((lane >> 4) << 2) + r;
        int col = c0 + n * 16 + (lane & 15);
        C[(size_t)row * NCOL + col] = f2bf(acc[m][n][r]);
      }
}

// ---------------- rope + transpose q,k -> [b][h][l][64] bf16 (q scaled by QSCL) ----------------
__global__ void k_rope(const u16* __restrict__ pre, const float* __restrict__ ctab,
                       const float* __restrict__ stab, u16* __restrict__ qt,
                       u16* __restrict__ kt) {
  int i = blockIdx.x * 256 + threadIdx.x;  // B*L*H*32
  int j = i & 31, hh = (i >> 5) & 15, l = (i >> 9) & 2047, b = i >> 20;
  float c = ctab[l * 32 + j], s = stab[l * 32 + j];
  const u16* prow = pre + (size_t)(b * NL + l) * NCOL;
  size_t oidx = ((size_t)((b * NH + hh) * NL + l)) * 64 + 2 * j;
  u16 a0 = prow[hh * 64 + 2 * j], a1 = prow[hh * 64 + 2 * j + 1];
  float x0 = bf2f(a0), x1 = bf2f(a1);
  qt[oidx] = f2bf((x0 * c - x1 * s) * QSCL);
  qt[oidx + 1] = f2bf((x0 * s + x1 * c) * QSCL);
  u16 b0 = prow[1024 + hh * 64 + 2 * j], b1 = prow[1024 + hh * 64 + 2 * j + 1];
  x0 = bf2f(b0);
  x1 = bf2f(b1);
  kt[oidx] = f2bf(x0 * c - x1 * s);
  kt[oidx + 1] = f2bf(x0 * s + x1 * c);
}

// ---------------- transpose v_low -> vT [b][h][r][L] bf16 ----------------
__global__ void k_vt(const u16* __restrict__ pre, u16* __restrict__ vT) {
  int i = blockIdx.x * 256 + threadIdx.x;  // B*H*16*L
  int l = i & 2047, r = (i >> 11) & 15, h = (i >> 15) & 15, b = i >> 19;
  vT[i] = pre[(size_t)(b * NL + l) * NCOL + 2048 + h * NRH + r];
}

// ---------------- flash attention (swapped QK^T, lane-local softmax, 2-phase) ----------------
// block: (b,h,qtile of 64 rows). wave handles 16 q-rows (q = lane&15 after swap).
// S^T[key][q] = mfma(K_frag, Q_frag); lane holds 16 keys of its q-row.
__global__ __launch_bounds__(256) void k_attn(const u16* __restrict__ qt,
                                              const u16* __restrict__ ktp,
                                              const u16* __restrict__ vT,
                                              const float* __restrict__ fbias,
                                              float* __restrict__ Oattn) {
  __shared__ char lds[28672];  // K dbuf 2x8192 | V dbuf 2x2048 | P per-wave 4x2048
  const int tid = threadIdx.x, wave = tid >> 6, lane = tid & 63;
  int blk = (int)blockIdx.x;
  blk = (blk & 7) * 128 + (blk >> 3);  // XCD swizzle (1024 % 8 == 0 -> bijective)
  const int qtile = blk & 31, h = (blk >> 5) & 15, b = blk >> 9;
  const size_t bh = (size_t)(b * NH + h);
  const u16* Q = qt + (bh * NL + (size_t)qtile * 64) * 64;
  const u16* K = ktp + bh * NL * 64;
  const u16* Vt = vT + bh * NRH * NL;
  const float* fbb = fbias + b * NL;
  char* Pl = lds + 20480 + wave * 2048;

  const int g = lane >> 4, qi = lane & 15;
  const int swq = (qi & 7) << 4;

  // Q fragments: lane holds Q[q=wave*16+qi][d = g*8..+7 (+32)]
  const int qr = wave * 16 + qi;
  bf16x8 qf0 = *(const bf16x8*)(Q + qr * 64 + g * 8);
  bf16x8 qf1 = *(const bf16x8*)(Q + qr * 64 + 32 + g * 8);

  f32x4 o = {0.f, 0.f, 0.f, 0.f};
  float M = -1e30f, Ls = 0.f;

  const int vr = tid >> 4, vcb = (tid & 15) * 8;  // V-stage: row, byte-col
  const int vdst = vr * 128 + vcb;
  const int vswz = vdst ^ ((vr & 7) << 4);

  // ---- prologue: stage tile 0 ----
  {
    uint2 vreg = *(const uint2*)((const char*)(Vt + (size_t)vr * NL) + vcb);
    const char* Kg = (const char*)K;
#pragma unroll
    for (int i = 0; i < 2; ++i) {
      int off = wave * 2048 + i * 1024 + lane * 16;
      int src = off ^ ((off >> 3) & 0x70);
      __builtin_amdgcn_global_load_lds(AS1(Kg + src), AS3(lds + wave * 2048 + i * 1024), 16, 0, 0);
    }
    *(uint2*)(lds + 16384 + vswz) = vreg;
  }

  int cur = 0;
  for (int t = 0; t < 32; ++t) {
    __syncthreads();  // buf[cur] ready (compiler drains vmcnt/lgkmcnt before barrier)
    const char* Kcur = lds + cur * 8192;
    const char* Vcur = lds + 16384 + cur * 2048;

    // issue in consumption order: fbias(t) -> V(t+1) -> K(t+1)
    const float* fbp = fbb + t * 64 + g * 4;
    f32x4 fb0 = *(const f32x4*)(fbp);
    f32x4 fb1 = *(const f32x4*)(fbp + 16);
    f32x4 fb2 = *(const f32x4*)(fbp + 32);
    f32x4 fb3 = *(const f32x4*)(fbp + 48);
    uint2 vreg;
    if (t < 31) {
      vreg = *(const uint2*)((const char*)(Vt + (size_t)vr * NL) + (t + 1) * 128 + vcb);
      const char* Kg = (const char*)(K + (size_t)(t + 1) * 64 * 64);
      char* Knxt = lds + (cur ^ 1) * 8192;
#pragma unroll
      for (int i = 0; i < 2; ++i) {
        int off = wave * 2048 + i * 1024 + lane * 16;
        int src = off ^ ((off >> 3) & 0x70);
        __builtin_amdgcn_global_load_lds(AS1(Kg + src), AS3(Knxt + wave * 2048 + i * 1024), 16, 0, 0);
      }
    }

    // ---- QK^T (swapped): s[n][r] = S[key=16n+4g+r][q=qi] + bias ----
    f32x4 s0, s1, s2, s3;
#define QK(n, dst, fbv)                                                    \
  {                                                                        \
    int row = n * 16 + qi;                                                 \
    int base = row * 128 + 16 * g;                                         \
    bf16x8 k0 = *(const bf16x8*)(Kcur + (base ^ swq));                     \
    bf16x8 k1 = *(const bf16x8*)(Kcur + ((base + 64) ^ swq));              \
    f32x4 z = {0.f, 0.f, 0.f, 0.f};                                        \
    z = __builtin_amdgcn_mfma_f32_16x16x32_bf16(k0, qf0, z, 0, 0, 0);      \
    z = __builtin_amdgcn_mfma_f32_16x16x32_bf16(k1, qf1, z, 0, 0, 0);      \
    dst[0] = z[0] + fbv[0]; dst[1] = z[1] + fbv[1];                        \
    dst[2] = z[2] + fbv[2]; dst[3] = z[3] + fbv[3];                        \
  }
    QK(0, s0, fb0) QK(1, s1, fb1) QK(2, s2, fb2) QK(3, s3, fb3)
#undef QK

    // ---- row max: in-lane tree over 16 + xor16/32 shuffles ----
    float m0 = fmaxf(fmaxf(s0[0], s0[1]), fmaxf(s0[2], s0[3]));
    float m1 = fmaxf(fmaxf(s1[0], s1[1]), fmaxf(s1[2], s1[3]));
    float m2 = fmaxf(fmaxf(s2[0], s2[1]), fmaxf(s2[2], s2[3]));
    float m3 = fmaxf(fmaxf(s3[0], s3[1]), fmaxf(s3[2], s3[3]));
    float mt = fmaxf(fmaxf(m0, m1), fmaxf(m2, m3));
    mt = fmaxf(mt, __shfl_xor(mt, 16));
    mt = fmaxf(mt, __shfl_xor(mt, 32));
    float Mn = fmaxf(M, mt);
    float e = exp2f(M - Mn);
    M = Mn;

    // ---- p = exp2(s-M), pack to bf16 (f2bf pairs), sum the ROUNDED values ----
    uint2 w0, w1, w2, w3;
    float rs = 0.f;
#define PP(sv, wv)                                                          \
  {                                                                         \
    float p0 = exp2f(sv[0] - M), p1 = exp2f(sv[1] - M);                     \
    float p2 = exp2f(sv[2] - M), p3 = exp2f(sv[3] - M);                     \
    u32 b0 = f2bf(p0), b1 = f2bf(p1), b2 = f2bf(p2), b3 = f2bf(p3);         \
    wv.x = b0 | (b1 << 16);                                                 \
    wv.y = b2 | (b3 << 16);                                                 \
    rs += __builtin_bit_cast(float, b0 << 16);                              \
    rs += __builtin_bit_cast(float, b1 << 16);                              \
    rs += __builtin_bit_cast(float, b2 << 16);                              \
    rs += __builtin_bit_cast(float, b3 << 16);                              \
  }
    PP(s0, w0) PP(s1, w1) PP(s2, w2) PP(s3, w3)
#undef PP
    rs += __shfl_xor(rs, 16);
    rs += __shfl_xor(rs, 32);
    Ls = Ls * e + rs;

    // ---- write P^T->[q][key] (packed b64, swizzled) ----
    {
      int d0 = qi * 128 + 8 * g;
      *(uint2*)(Pl + ((d0) ^ swq)) = w0;
      *(uint2*)(Pl + ((d0 + 32) ^ swq)) = w1;
      *(uint2*)(Pl + ((d0 + 64) ^ swq)) = w2;
      *(uint2*)(Pl + ((d0 + 96) ^ swq)) = w3;
    }

    // ---- V(t+1) LDS write (late; overlaps) ----
    if (t < 31) *(uint2*)(lds + 16384 + (cur ^ 1) * 2048 + vswz) = vreg;

    // ---- rescale o by e (o rows are q=4g+i -> shuffle e) ----
#pragma unroll
    for (int i = 0; i < 4; ++i) {
      float ei = __shfl(e, g * 4 + i);
      o[i] *= ei;
    }

    // ---- PV: o += P[q][k] * V[k][r] ----
#pragma unroll
    for (int c = 0; c < 2; ++c) {
      int ab = qi * 128 + 16 * g + 64 * c;
      int sa = ab ^ swq;
      bf16x8 pf = *(const bf16x8*)(Pl + sa);
      bf16x8 vf = *(const bf16x8*)(Vcur + sa);
      o = __builtin_amdgcn_mfma_f32_16x16x32_bf16(pf, vf, o, 0, 0, 0);
    }
    cur ^= 1;
  }

  // ---- epilogue: divide by L (shuffle into o-domain), write ----
  const size_t qrow0 = bh * NL + (size_t)qtile * 64 + wave * 16;
#pragma unroll
  for (int i = 0; i < 4; ++i) {
    float Li = __shfl(Ls, g * 4 + i);
    Oattn[(qrow0 + g * 4 + i) * NRH + qi] = o[i] / Li;
  }
}

// ---------------- final projection ----------------
__global__ void k_proj(const float* __restrict__ Oattn, const float* __restrict__ V,
                       float* __restrict__ out) {
  int bl = blockIdx.x;  // B*L
  int b = bl >> 11, l = bl & 2047;
  __shared__ float sO[256];
  int tid = threadIdx.x;
  sO[tid] = Oattn[((size_t)(b * NH + (tid >> 4)) * NL + l) * NRH + (tid & 15)];
  __syncthreads();
#pragma unroll
  for (int p = 0; p < 4; ++p) {
    int h = (tid >> 6) + p * 4;
    int d = tid & 63;
    float acc = 0.f;
    const float* Vh = V + (size_t)(h * NRH) * NHD + d;
    const float* Oh = sO + h * NRH;
#pragma unroll
    for (int r = 0; r < 16; ++r) acc += Oh[r] * Vh[(size_t)r * NHD];
    out[(size_t)bl * NDM + h * NHD + d] = acc;
  }
}

extern "C" void kernel_launch(void* const* d_in, const int* in_sizes, int n_in,
                              void* d_out, int out_size, void* d_ws, size_t ws_size,
                              hipStream_t stream) {
  (void)in_sizes; (void)n_in; (void)out_size; (void)ws_size;
  const float* x  = (const float*)d_in[0];
  const float* Wq = (const float*)d_in[1];
  const float* Wk = (const float*)d_in[2];
  const float* Wv = (const float*)d_in[3];
  const float* U  = (const float*)d_in[4];
  const float* Vm = (const float*)d_in[5];
  const int* mask = (const int*)d_in[6];
  float* out = (float*)d_out;
  char* ws = (char*)d_ws;

  u16* Wall   = (u16*)(ws);               // 4,718,592 B
  u16* xb     = (u16*)(ws + 4718592);     // 8,388,608 B (dead after GEMM)
  u16* pre    = (u16*)(ws + 13107200);    // 18,874,368 B
  u16* qt     = (u16*)(ws + 31981568);    // 8,388,608 B
  u16* ktb    = (u16*)(ws + 40370176);    // 8,388,608 B
  u16* vT     = (u16*)(ws + 48758784);    // 2,097,152 B
  float* ctab = (float*)(ws + 50855936);  // 262,144 B
  float* stab = (float*)(ws + 51118080);  // 262,144 B
  float* Oattn = (float*)(ws + 4718592);  // reuse xb region: 4 MB
  float* fbias = (float*)(ws + 8912896);  // reuse xb region tail: 16 KB

  k_prep_weff<<<dim3(9216), dim3(256), 0, stream>>>(Wq, Wk, Wv, U, Wall);
  k_cast_x<<<dim3(8192), dim3(256), 0, stream>>>(x, xb);
  k_rope_tab<<<dim3(256), dim3(256), 0, stream>>>(ctab, stab);
  k_gemm<<<dim3(32, 18), dim3(256), 0, stream>>>(xb, Wall, pre);
  k_fbias<<<dim3(16), dim3(256), 0, stream>>>(mask, fbias);
  k_rope<<<dim3(8192), dim3(256), 0, stream>>>(pre, ctab, stab, qt, ktb);
  k_vt<<<dim3(4096), dim3(256), 0, stream>>>(pre, vT);
  k_attn<<<dim3(1024), dim3(256), 0, stream>>>(qt, ktb, vT, fbias, Oattn);
  k_proj<<<dim3(4096), dim3(256), 0, stream>>>(Oattn, Vm, out);
}

// Round 6
// 141.942 us; speedup vs baseline: 1.2045x; 1.0790x over previous
//
#include <hip/hip_runtime.h>
#include <hip/hip_bf16.h>

typedef unsigned short u16;
typedef unsigned int u32;
typedef __bf16 bf16x8 __attribute__((ext_vector_type(8)));
typedef float f32x4 __attribute__((ext_vector_type(4)));

#define NB 2
#define NL 2048
#define NDM 1024
#define NH 16
#define NHD 64
#define NRH 16
#define NCOL 2304  // 1024 q | 1024 k | 256 v

// 0.125 * log2(e): folded into q at RoPE time so attn works in exp2 domain
#define QSCL 0.18033688011112042f

#define AS1(p) ((const __attribute__((address_space(1))) void*)(p))
#define AS3(p) ((__attribute__((address_space(3))) void*)(p))

__device__ __forceinline__ u16 f2bf(float f) {
  u32 u = __builtin_bit_cast(u32, f);
  u32 r = (u + 0x7fffu + ((u >> 16) & 1u)) >> 16;
  return (u16)r;
}
__device__ __forceinline__ float bf2f(u16 b) {
  return __builtin_bit_cast(float, (u32)b << 16);
}
// pack two floats to bf16x2 word (RNE)
__device__ __forceinline__ u32 pk2(float lo, float hi) {
  return (u32)f2bf(lo) | ((u32)f2bf(hi) << 16);
}

// ---------------- prep: effective weights  Wall[2304][1024] bf16 ----------------
__global__ void k_prep_weff(const float* __restrict__ Wq, const float* __restrict__ Wk,
                            const float* __restrict__ Wv, const float* __restrict__ U,
                            u16* __restrict__ Wall) {
  int idx = blockIdx.x * 256 + threadIdx.x;  // NCOL*1024
  int col = idx & 1023;
  int row = idx >> 10;
  float acc;
  if (row < 2048) {
    const float* W = (row < 1024) ? Wq : Wk;
    int rr = row & 1023;
    int h = rr >> 6, d = rr & 63;
    const float* Uh = U + (h * NHD + d) * NRH;
    const float* Wr = W + (size_t)(h * NRH) * NDM + col;
    acc = 0.f;
#pragma unroll
    for (int r = 0; r < 16; ++r) acc += Uh[r] * Wr[(size_t)r * NDM];
  } else {
    acc = Wv[(size_t)(row - 2048) * NDM + col];
  }
  Wall[idx] = f2bf(acc);
}

// ---------------- cast x -> bf16 ----------------
__global__ void k_cast_x(const float* __restrict__ x, u16* __restrict__ xb) {
  int i = blockIdx.x * 256 + threadIdx.x;
  float2 v = *(const float2*)(x + (size_t)i * 2);
  ushort2 o;
  o.x = f2bf(v.x);
  o.y = f2bf(v.y);
  *(ushort2*)(xb + (size_t)i * 2) = o;
}

// ---------------- rope cos/sin table [L][32] ----------------
__global__ void k_rope_tab(float* __restrict__ ctab, float* __restrict__ stab) {
  int i = blockIdx.x * 256 + threadIdx.x;
  if (i >= NL * 32) return;
  int l = i >> 5, j = i & 31;
  float theta = 1.0f / powf(10000.0f, (float)j * (1.0f / 32.0f));
  float ang = (float)l * theta;
  ctab[i] = cosf(ang);
  stab[i] = sinf(ang);
}

// ---------------- mask -> float bias (0 / -1e30) ----------------
__global__ void k_fbias(const int* __restrict__ mask, float* __restrict__ fb) {
  int i = blockIdx.x * 256 + threadIdx.x;  // B*L = 4096
  fb[i] = mask[i] ? 0.f : -1e30f;
}

// ---------------- GEMM: pre[4096][2304] = xb[4096][1024] @ Wall^T ----------------
__global__ __launch_bounds__(256) void k_gemm(const u16* __restrict__ A,
                                              const u16* __restrict__ Bm,
                                              u16* __restrict__ C) {
  __shared__ char lds[32768];
  const int tid = threadIdx.x;
  const int wave = tid >> 6, lane = tid & 63;
  const int bm = blockIdx.x, bn = blockIdx.y;
  const int wr = wave >> 1, wc = wave & 1;
  const char* Ag = (const char*)(A + (size_t)bm * 128 * NDM);
  const char* Bg = (const char*)(Bm + (size_t)bn * 128 * NDM);
  f32x4 acc[4][4] = {};
  for (int kt = 0; kt < 16; ++kt) {
    __syncthreads();
#pragma unroll
    for (int i = 0; i < 4; ++i) {
      int off = wave * 4096 + i * 1024 + lane * 16;
      int src = off ^ ((off >> 3) & 0x70);
      int ga = (src >> 7) * 2048 + kt * 128 + (src & 127);
      __builtin_amdgcn_global_load_lds(AS1(Ag + ga), AS3(lds + wave * 4096 + i * 1024), 16, 0, 0);
      __builtin_amdgcn_global_load_lds(AS1(Bg + ga), AS3(lds + 16384 + wave * 4096 + i * 1024), 16, 0, 0);
    }
    __syncthreads();
#pragma unroll
    for (int kk = 0; kk < 2; ++kk) {
      bf16x8 af[4], bfr[4];
#pragma unroll
      for (int m = 0; m < 4; ++m) {
        int row = wr * 64 + m * 16 + (lane & 15);
        int byte = row * 128 + kk * 64 + ((lane >> 4) << 4);
        af[m] = *(const bf16x8*)(lds + (byte ^ ((row & 7) << 4)));
      }
#pragma unroll
      for (int n = 0; n < 4; ++n) {
        int row = wc * 64 + n * 16 + (lane & 15);
        int byte = row * 128 + kk * 64 + ((lane >> 4) << 4);
        bfr[n] = *(const bf16x8*)(lds + 16384 + (byte ^ ((row & 7) << 4)));
      }
#pragma unroll
      for (int m = 0; m < 4; ++m)
#pragma unroll
        for (int n = 0; n < 4; ++n)
          acc[m][n] = __builtin_amdgcn_mfma_f32_16x16x32_bf16(af[m], bfr[n], acc[m][n], 0, 0, 0);
    }
  }
  const int r0 = bm * 128 + wr * 64, c0 = bn * 128 + wc * 64;
#pragma unroll
  for (int m = 0; m < 4; ++m)
#pragma unroll
    for (int n = 0; n < 4; ++n)
#pragma unroll
      for (int r = 0; r < 4; ++r) {
        int row = r0 + m * 16 + ((lane >> 4) << 2) + r;
        int col = c0 + n * 16 + (lane & 15);
        C[(size_t)row * NCOL + col] = f2bf(acc[m][n][r]);
      }
}

// ---------------- rope + transpose q,k -> [b][h][l][64] bf16 (q scaled by QSCL) ----------------
__global__ void k_rope(const u16* __restrict__ pre, const float* __restrict__ ctab,
                       const float* __restrict__ stab, u16* __restrict__ qt,
                       u16* __restrict__ kt) {
  int i = blockIdx.x * 256 + threadIdx.x;  // B*L*H*32
  int j = i & 31, hh = (i >> 5) & 15, l = (i >> 9) & 2047, b = i >> 20;
  float c = ctab[l * 32 + j], s = stab[l * 32 + j];
  const u16* prow = pre + (size_t)(b * NL + l) * NCOL;
  size_t oidx = ((size_t)((b * NH + hh) * NL + l)) * 64 + 2 * j;
  u16 a0 = prow[hh * 64 + 2 * j], a1 = prow[hh * 64 + 2 * j + 1];
  float x0 = bf2f(a0), x1 = bf2f(a1);
  qt[oidx] = f2bf((x0 * c - x1 * s) * QSCL);
  qt[oidx + 1] = f2bf((x0 * s + x1 * c) * QSCL);
  u16 b0 = prow[1024 + hh * 64 + 2 * j], b1 = prow[1024 + hh * 64 + 2 * j + 1];
  x0 = bf2f(b0);
  x1 = bf2f(b1);
  kt[oidx] = f2bf(x0 * c - x1 * s);
  kt[oidx + 1] = f2bf(x0 * s + x1 * c);
}

// ---------------- transpose v_low -> vT_sigma [b][h][r][L] bf16 ----------------
// Within each 64-key block, column p holds key k(p) = 16*((p>>5)&1) + 32*((p>>2)&1)
// + 4*((p>>3)&3) + (p&3)  (sigma-order so PV A-frags stay in registers in k_attn).
__global__ void k_vt(const u16* __restrict__ pre, u16* __restrict__ vT) {
  __shared__ u16 s[64][16];  // [l-local][r]
  int blk = blockIdx.x;  // B*H*32
  int t = blk & 31, h = (blk >> 5) & 15, b = blk >> 9;
  int tid = threadIdx.x;
  {
    int l = tid >> 2, rq = (tid & 3) * 4;
    const u16* src = pre + (size_t)(b * NL + t * 64 + l) * NCOL + 2048 + h * NRH + rq;
    *(uint2*)&s[l][rq] = *(const uint2*)src;
  }
  __syncthreads();
  {
    int r = tid >> 4, pq = (tid & 15) * 4;
    int kb = ((pq >> 5) & 1) * 16 + ((pq >> 2) & 1) * 32 + ((pq >> 3) & 3) * 4;
    ushort4 o;
    o.x = s[kb + 0][r];
    o.y = s[kb + 1][r];
    o.z = s[kb + 2][r];
    o.w = s[kb + 3][r];
    *(ushort4*)(vT + ((size_t)((b * NH + h) * NRH + r)) * NL + t * 64 + pq) = o;
  }
}

// ---------------- flash attention v3b ----------------
// Swapped QK^T; P stays in registers (sigma k-order); V direct global loads;
// K staged in LDS (dbuf, wave-uniform dst + pre-swizzled source); defer-rescale.
__global__ __launch_bounds__(256) void k_attn(const u16* __restrict__ qt,
                                              const u16* __restrict__ ktp,
                                              const u16* __restrict__ vT,
                                              const float* __restrict__ fbias,
                                              float* __restrict__ Oattn) {
  __shared__ char lds[16384];  // K double buffer 2 x 8KB
  const int tid = threadIdx.x, wave = tid >> 6, lane = tid & 63;
  int blk = (int)blockIdx.x;
  blk = (blk & 7) * 128 + (blk >> 3);  // XCD swizzle (1024 % 8 == 0 -> bijective)
  const int qtile = blk & 31, h = (blk >> 5) & 15, b = blk >> 9;
  const size_t bh = (size_t)(b * NH + h);
  const u16* Q = qt + (bh * NL + (size_t)qtile * 64) * 64;
  const u16* K = ktp + bh * NL * 64;
  const u16* Vt = vT + bh * NRH * NL;
  const float* fbb = fbias + b * NL;

  const int g = lane >> 4, qi = lane & 15;
  const int swq = (qi & 7) << 4;

  // Q fragments: lane supplies Q[q=wave*16+qi][d = g*8..+7 (and +32)]
  const int qr = wave * 16 + qi;
  bf16x8 qf0 = *(const bf16x8*)(Q + qr * 64 + g * 8);
  bf16x8 qf1 = *(const bf16x8*)(Q + qr * 64 + 32 + g * 8);

  f32x4 o = {0.f, 0.f, 0.f, 0.f};
  float M = -1e30f, Ls = 0.f;

  // loop-invariant bases
  const u16* Vrow = Vt + (size_t)qi * NL + g * 8;  // + t*64 (+32)
  const float* fbg = fbb + g * 4;                  // + t*64 (+ n*16)
  // K ds_read offsets (loop-invariant, swizzled)
  int koff[4][2];
#pragma unroll
  for (int n = 0; n < 4; ++n)
#pragma unroll
    for (int dc = 0; dc < 2; ++dc)
      koff[n][dc] = (((n * 16 + qi) * 128 + dc * 64 + g * 16) ^ swq);

  // ---- prologue: stage K tile 0 (wave-uniform LDS dst; swizzle in source) ----
#pragma unroll
  for (int i = 0; i < 2; ++i) {
    int off = wave * 2048 + i * 1024 + lane * 16;
    int src = off ^ ((off >> 3) & 0x70);
    __builtin_amdgcn_global_load_lds(AS1((const char*)K + src),
                                     AS3(lds + wave * 2048 + i * 1024), 16, 0, 0);
  }

  int cur = 0;
  for (int t = 0; t < 32; ++t) {
    __syncthreads();  // K buf[cur] ready (vmcnt drained before barrier)
    // issue K(t+1) stage into the other buffer
    if (t < 31) {
      const char* Kg = (const char*)(K + (size_t)(t + 1) * 4096);
      char* Kn = lds + (cur ^ 1) * 8192;
#pragma unroll
      for (int i = 0; i < 2; ++i) {
        int off = wave * 2048 + i * 1024 + lane * 16;
        int src = off ^ ((off >> 3) & 0x70);
        __builtin_amdgcn_global_load_lds(AS1(Kg + src),
                                         AS3(Kn + wave * 2048 + i * 1024), 16, 0, 0);
      }
    }
    const char* Kcur = lds + cur * 8192;

    // direct loads: bias (4x f32x4) and V (2x bf16x8, sigma-order)
    const float* fbt = fbg + t * 64;
    f32x4 fb0 = *(const f32x4*)(fbt);
    f32x4 fb1 = *(const f32x4*)(fbt + 16);
    f32x4 fb2 = *(const f32x4*)(fbt + 32);
    f32x4 fb3 = *(const f32x4*)(fbt + 48);
    const u16* Vtt = Vrow + t * 64;
    bf16x8 vf0 = *(const bf16x8*)(Vtt);
    bf16x8 vf1 = *(const bf16x8*)(Vtt + 32);

    // ---- QK^T (swapped): s_n[r] = S[key=16n+4g+r][q=qi] + bias ----
    f32x4 s0, s1, s2, s3;
#define QK(n, dst, fbv)                                                    \
  {                                                                        \
    bf16x8 k0 = *(const bf16x8*)(Kcur + koff[n][0]);                       \
    bf16x8 k1 = *(const bf16x8*)(Kcur + koff[n][1]);                       \
    f32x4 z = {0.f, 0.f, 0.f, 0.f};                                        \
    z = __builtin_amdgcn_mfma_f32_16x16x32_bf16(k0, qf0, z, 0, 0, 0);      \
    z = __builtin_amdgcn_mfma_f32_16x16x32_bf16(k1, qf1, z, 0, 0, 0);      \
    dst[0] = z[0] + fbv[0]; dst[1] = z[1] + fbv[1];                        \
    dst[2] = z[2] + fbv[2]; dst[3] = z[3] + fbv[3];                        \
  }
    QK(0, s0, fb0) QK(1, s1, fb1) QK(2, s2, fb2) QK(3, s3, fb3)
#undef QK

    // ---- row max (16 in-lane + xor16/32) ----
    float m0 = fmaxf(fmaxf(s0[0], s0[1]), fmaxf(s0[2], s0[3]));
    float m1 = fmaxf(fmaxf(s1[0], s1[1]), fmaxf(s1[2], s1[3]));
    float m2 = fmaxf(fmaxf(s2[0], s2[1]), fmaxf(s2[2], s2[3]));
    float m3 = fmaxf(fmaxf(s3[0], s3[1]), fmaxf(s3[2], s3[3]));
    float mt = fmaxf(fmaxf(m0, m1), fmaxf(m2, m3));
    mt = fmaxf(mt, __shfl_xor(mt, 16));
    mt = fmaxf(mt, __shfl_xor(mt, 32));

    // ---- defer-rescale (T13, exp2 domain, THR=8) ----
    if (__any(mt > M + 8.f)) {
      float Mn = fmaxf(M, mt);
      float e = exp2f(M - Mn);
      M = Mn;
      Ls *= e;
#pragma unroll
      for (int i = 0; i < 4; ++i) o[i] *= __shfl(e, g * 4 + i);
    }

    // ---- p = exp2(s-M); pack (RNE); sum unrounded ----
    float p00 = exp2f(s0[0] - M), p01 = exp2f(s0[1] - M), p02 = exp2f(s0[2] - M), p03 = exp2f(s0[3] - M);
    float p10 = exp2f(s1[0] - M), p11 = exp2f(s1[1] - M), p12 = exp2f(s1[2] - M), p13 = exp2f(s1[3] - M);
    float p20 = exp2f(s2[0] - M), p21 = exp2f(s2[1] - M), p22 = exp2f(s2[2] - M), p23 = exp2f(s2[3] - M);
    float p30 = exp2f(s3[0] - M), p31 = exp2f(s3[1] - M), p32 = exp2f(s3[2] - M), p33 = exp2f(s3[3] - M);
    float rs = (((p00 + p01) + (p02 + p03)) + ((p10 + p11) + (p12 + p13))) +
               (((p20 + p21) + (p22 + p23)) + ((p30 + p31) + (p32 + p33)));
    rs += __shfl_xor(rs, 16);
    rs += __shfl_xor(rs, 32);
    Ls += rs;

    // PV A-frags directly from registers (sigma order):
    // pf0 = keys{n=0}(slots 0..3) + keys{n=2}(slots 4..7); pf1 = {n=1} + {n=3}
    uint4 wa{pk2(p00, p01), pk2(p02, p03), pk2(p20, p21), pk2(p22, p23)};
    uint4 wb{pk2(p10, p11), pk2(p12, p13), pk2(p30, p31), pk2(p32, p33)};
    bf16x8 pf0 = __builtin_bit_cast(bf16x8, wa);
    bf16x8 pf1 = __builtin_bit_cast(bf16x8, wb);

    // ---- PV ----
    o = __builtin_amdgcn_mfma_f32_16x16x32_bf16(pf0, vf0, o, 0, 0, 0);
    o = __builtin_amdgcn_mfma_f32_16x16x32_bf16(pf1, vf1, o, 0, 0, 0);
    cur ^= 1;
  }

  // ---- epilogue ----
  const size_t qrow0 = bh * NL + (size_t)qtile * 64 + wave * 16;
#pragma unroll
  for (int i = 0; i < 4; ++i) {
    float Li = __shfl(Ls, g * 4 + i);
    Oattn[(qrow0 + g * 4 + i) * NRH + qi] = o[i] / Li;
  }
}

// ---------------- final projection ----------------
__global__ void k_proj(const float* __restrict__ Oattn, const float* __restrict__ V,
                       float* __restrict__ out) {
  int bl = blockIdx.x;  // B*L
  int b = bl >> 11, l = bl & 2047;
  __shared__ float sO[256];
  int tid = threadIdx.x;
  sO[tid] = Oattn[((size_t)(b * NH + (tid >> 4)) * NL + l) * NRH + (tid & 15)];
  __syncthreads();
#pragma unroll
  for (int p = 0; p < 4; ++p) {
    int h = (tid >> 6) + p * 4;
    int d = tid & 63;
    float acc = 0.f;
    const float* Vh = V + (size_t)(h * NRH) * NHD + d;
    const float* Oh = sO + h * NRH;
#pragma unroll
    for (int r = 0; r < 16; ++r) acc += Oh[r] * Vh[(size_t)r * NHD];
    out[(size_t)bl * NDM + h * NHD + d] = acc;
  }
}

extern "C" void kernel_launch(void* const* d_in, const int* in_sizes, int n_in,
                              void* d_out, int out_size, void* d_ws, size_t ws_size,
                              hipStream_t stream) {
  (void)in_sizes; (void)n_in; (void)out_size; (void)ws_size;
  const float* x  = (const float*)d_in[0];
  const float* Wq = (const float*)d_in[1];
  const float* Wk = (const float*)d_in[2];
  const float* Wv = (const float*)d_in[3];
  const float* U  = (const float*)d_in[4];
  const float* Vm = (const float*)d_in[5];
  const int* mask = (const int*)d_in[6];
  float* out = (float*)d_out;
  char* ws = (char*)d_ws;

  u16* Wall   = (u16*)(ws);               // 4,718,592 B
  u16* xb     = (u16*)(ws + 4718592);     // 8,388,608 B (dead after GEMM)
  u16* pre    = (u16*)(ws + 13107200);    // 18,874,368 B
  u16* qt     = (u16*)(ws + 31981568);    // 8,388,608 B
  u16* ktb    = (u16*)(ws + 40370176);    // 8,388,608 B
  u16* vT     = (u16*)(ws + 48758784);    // 2,097,152 B
  float* ctab = (float*)(ws + 50855936);  // 262,144 B
  float* stab = (float*)(ws + 51118080);  // 262,144 B
  float* Oattn = (float*)(ws + 4718592);  // reuse xb region: 4 MB
  float* fbias = (float*)(ws + 8912896);  // reuse xb region tail: 16 KB

  k_prep_weff<<<dim3(9216), dim3(256), 0, stream>>>(Wq, Wk, Wv, U, Wall);
  k_cast_x<<<dim3(8192), dim3(256), 0, stream>>>(x, xb);
  k_rope_tab<<<dim3(256), dim3(256), 0, stream>>>(ctab, stab);
  k_gemm<<<dim3(32, 18), dim3(256), 0, stream>>>(xb, Wall, pre);
  k_fbias<<<dim3(16), dim3(256), 0, stream>>>(mask, fbias);
  k_rope<<<dim3(8192), dim3(256), 0, stream>>>(pre, ctab, stab, qt, ktb);
  k_vt<<<dim3(1024), dim3(256), 0, stream>>>(pre, vT);
  k_attn<<<dim3(1024), dim3(256), 0, stream>>>(qt, ktb, vT, fbias, Oattn);
  k_proj<<<dim3(4096), dim3(256), 0, stream>>>(Oattn, Vm, out);
}

// Round 7
// 126.441 us; speedup vs baseline: 1.3522x; 1.1226x over previous
//
#include <hip/hip_runtime.h>
#include <hip/hip_bf16.h>

typedef unsigned short u16;
typedef unsigned int u32;
typedef __bf16 bf16x8 __attribute__((ext_vector_type(8)));
typedef float f32x4 __attribute__((ext_vector_type(4)));

#define NB 2
#define NL 2048
#define NDM 1024
#define NH 16
#define NHD 64
#define NRH 16
#define NCOL 2304  // 1024 q | 1024 k | 256 v

// 0.125 * log2(e): folded into q at RoPE time so attn works in exp2 domain
#define QSCL 0.18033688011112042f

#define AS1(p) ((const __attribute__((address_space(1))) void*)(p))
#define AS3(p) ((__attribute__((address_space(3))) void*)(p))

__device__ __forceinline__ u16 f2bf(float f) {
  u32 u = __builtin_bit_cast(u32, f);
  u32 r = (u + 0x7fffu + ((u >> 16) & 1u)) >> 16;
  return (u16)r;
}
__device__ __forceinline__ float bf2f(u16 b) {
  return __builtin_bit_cast(float, (u32)b << 16);
}

// ---------------- prep: effective weights  Wall[2304][1024] bf16 ----------------
__global__ void k_prep_weff(const float* __restrict__ Wq, const float* __restrict__ Wk,
                            const float* __restrict__ Wv, const float* __restrict__ U,
                            u16* __restrict__ Wall) {
  int idx = blockIdx.x * 256 + threadIdx.x;  // NCOL*1024
  int col = idx & 1023;
  int row = idx >> 10;
  float acc;
  if (row < 2048) {
    const float* W = (row < 1024) ? Wq : Wk;
    int rr = row & 1023;
    int h = rr >> 6, d = rr & 63;
    const float* Uh = U + (h * NHD + d) * NRH;
    const float* Wr = W + (size_t)(h * NRH) * NDM + col;
    acc = 0.f;
#pragma unroll
    for (int r = 0; r < 16; ++r) acc += Uh[r] * Wr[(size_t)r * NDM];
  } else {
    acc = Wv[(size_t)(row - 2048) * NDM + col];
  }
  Wall[idx] = f2bf(acc);
}

// ---------------- cast x -> bf16 ----------------
__global__ void k_cast_x(const float* __restrict__ x, u16* __restrict__ xb) {
  int i = blockIdx.x * 256 + threadIdx.x;
  float2 v = *(const float2*)(x + (size_t)i * 2);
  ushort2 o;
  o.x = f2bf(v.x);
  o.y = f2bf(v.y);
  *(ushort2*)(xb + (size_t)i * 2) = o;
}

// ---------------- rope cos/sin table [L][32] ----------------
__global__ void k_rope_tab(float* __restrict__ ctab, float* __restrict__ stab) {
  int i = blockIdx.x * 256 + threadIdx.x;
  if (i >= NL * 32) return;
  int l = i >> 5, j = i & 31;
  float theta = 1.0f / powf(10000.0f, (float)j * (1.0f / 32.0f));
  float ang = (float)l * theta;
  ctab[i] = cosf(ang);
  stab[i] = sinf(ang);
}

// ---------------- mask -> float bias (0 / -1e30) ----------------
__global__ void k_fbias(const int* __restrict__ mask, float* __restrict__ fb) {
  int i = blockIdx.x * 256 + threadIdx.x;  // B*L = 4096
  fb[i] = mask[i] ? 0.f : -1e30f;
}

// ---------------- GEMM: pre[4096][2304] = xb[4096][1024] @ Wall^T ----------------
__global__ __launch_bounds__(256) void k_gemm(const u16* __restrict__ A,
                                              const u16* __restrict__ Bm,
                                              u16* __restrict__ C) {
  __shared__ char lds[32768];
  const int tid = threadIdx.x;
  const int wave = tid >> 6, lane = tid & 63;
  const int bm = blockIdx.x, bn = blockIdx.y;
  const int wr = wave >> 1, wc = wave & 1;
  const char* Ag = (const char*)(A + (size_t)bm * 128 * NDM);
  const char* Bg = (const char*)(Bm + (size_t)bn * 128 * NDM);
  f32x4 acc[4][4] = {};
  for (int kt = 0; kt < 16; ++kt) {
    __syncthreads();
#pragma unroll
    for (int i = 0; i < 4; ++i) {
      int off = wave * 4096 + i * 1024 + lane * 16;
      int src = off ^ ((off >> 3) & 0x70);
      int ga = (src >> 7) * 2048 + kt * 128 + (src & 127);
      __builtin_amdgcn_global_load_lds(AS1(Ag + ga), AS3(lds + wave * 4096 + i * 1024), 16, 0, 0);
      __builtin_amdgcn_global_load_lds(AS1(Bg + ga), AS3(lds + 16384 + wave * 4096 + i * 1024), 16, 0, 0);
    }
    __syncthreads();
#pragma unroll
    for (int kk = 0; kk < 2; ++kk) {
      bf16x8 af[4], bfr[4];
#pragma unroll
      for (int m = 0; m < 4; ++m) {
        int row = wr * 64 + m * 16 + (lane & 15);
        int byte = row * 128 + kk * 64 + ((lane >> 4) << 4);
        af[m] = *(const bf16x8*)(lds + (byte ^ ((row & 7) << 4)));
      }
#pragma unroll
      for (int n = 0; n < 4; ++n) {
        int row = wc * 64 + n * 16 + (lane & 15);
        int byte = row * 128 + kk * 64 + ((lane >> 4) << 4);
        bfr[n] = *(const bf16x8*)(lds + 16384 + (byte ^ ((row & 7) << 4)));
      }
#pragma unroll
      for (int m = 0; m < 4; ++m)
#pragma unroll
        for (int n = 0; n < 4; ++n)
          acc[m][n] = __builtin_amdgcn_mfma_f32_16x16x32_bf16(af[m], bfr[n], acc[m][n], 0, 0, 0);
    }
  }
  const int r0 = bm * 128 + wr * 64, c0 = bn * 128 + wc * 64;
#pragma unroll
  for (int m = 0; m < 4; ++m)
#pragma unroll
    for (int n = 0; n < 4; ++n)
#pragma unroll
      for (int r = 0; r < 4; ++r) {
        int row = r0 + m * 16 + ((lane >> 4) << 2) + r;
        int col = c0 + n * 16 + (lane & 15);
        C[(size_t)row * NCOL + col] = f2bf(acc[m][n][r]);
      }
}

// ---------------- rope + transpose q,k -> [b][h][l][64] bf16 (q scaled by QSCL) ----------------
__global__ void k_rope(const u16* __restrict__ pre, const float* __restrict__ ctab,
                       const float* __restrict__ stab, u16* __restrict__ qt,
                       u16* __restrict__ kt) {
  int i = blockIdx.x * 256 + threadIdx.x;  // B*L*H*32
  int j = i & 31, hh = (i >> 5) & 15, l = (i >> 9) & 2047, b = i >> 20;
  float c = ctab[l * 32 + j], s = stab[l * 32 + j];
  const u16* prow = pre + (size_t)(b * NL + l) * NCOL;
  size_t oidx = ((size_t)((b * NH + hh) * NL + l)) * 64 + 2 * j;
  u16 a0 = prow[hh * 64 + 2 * j], a1 = prow[hh * 64 + 2 * j + 1];
  float x0 = bf2f(a0), x1 = bf2f(a1);
  qt[oidx] = f2bf((x0 * c - x1 * s) * QSCL);
  qt[oidx + 1] = f2bf((x0 * s + x1 * c) * QSCL);
  u16 b0 = prow[1024 + hh * 64 + 2 * j], b1 = prow[1024 + hh * 64 + 2 * j + 1];
  x0 = bf2f(b0);
  x1 = bf2f(b1);
  kt[oidx] = f2bf(x0 * c - x1 * s);
  kt[oidx + 1] = f2bf(x0 * s + x1 * c);
}

// ---------------- transpose v_low -> vT_sigma [b][h][r][L] bf16 ----------------
// Within each 64-key block, column p holds key k(p) = 16*((p>>5)&1) + 32*((p>>2)&1)
// + 4*((p>>3)&3) + (p&3)  (sigma-order so PV A-frags stay in registers in k_attn).
__global__ void k_vt(const u16* __restrict__ pre, u16* __restrict__ vT) {
  __shared__ u16 s[64][16];  // [l-local][r]
  int blk = blockIdx.x;  // B*H*32
  int t = blk & 31, h = (blk >> 5) & 15, b = blk >> 9;
  int tid = threadIdx.x;
  {
    int l = tid >> 2, rq = (tid & 3) * 4;
    const u16* src = pre + (size_t)(b * NL + t * 64 + l) * NCOL + 2048 + h * NRH + rq;
    *(uint2*)&s[l][rq] = *(const uint2*)src;
  }
  __syncthreads();
  {
    int r = tid >> 4, pq = (tid & 15) * 4;
    int kb = ((pq >> 5) & 1) * 16 + ((pq >> 2) & 1) * 32 + ((pq >> 3) & 3) * 4;
    ushort4 o;
    o.x = s[kb + 0][r];
    o.y = s[kb + 1][r];
    o.z = s[kb + 2][r];
    o.w = s[kb + 3][r];
    *(ushort4*)(vT + ((size_t)((b * NH + h) * NRH + r)) * NL + t * 64 + pq) = o;
  }
}

// ---------------- flash attention v4 ----------------
// Swapped QK^T (bias rides MFMA C-in); P in registers (sigma k-order);
// V direct global loads; K LDS dbuf; native exp2/cvt_pk; defer-rescale.
__global__ __launch_bounds__(256) void k_attn(const u16* __restrict__ qt,
                                              const u16* __restrict__ ktp,
                                              const u16* __restrict__ vT,
                                              const float* __restrict__ fbias,
                                              float* __restrict__ Oattn) {
  __shared__ char lds[16384];  // K double buffer 2 x 8KB
  const int tid = threadIdx.x, wave = tid >> 6, lane = tid & 63;
  int blk = (int)blockIdx.x;
  blk = (blk & 7) * 128 + (blk >> 3);  // XCD swizzle (1024 % 8 == 0 -> bijective)
  const int qtile = blk & 31, h = (blk >> 5) & 15, b = blk >> 9;
  const size_t bh = (size_t)(b * NH + h);
  const u16* Q = qt + (bh * NL + (size_t)qtile * 64) * 64;
  const u16* K = ktp + bh * NL * 64;
  const u16* Vt = vT + bh * NRH * NL;
  const float* fbb = fbias + b * NL;

  const int g = lane >> 4, qi = lane & 15;
  const int swq = (qi & 7) << 4;

  // Q fragments: lane supplies Q[q=wave*16+qi][d = g*8..+7 (and +32)]
  const int qr = wave * 16 + qi;
  bf16x8 qf0 = *(const bf16x8*)(Q + qr * 64 + g * 8);
  bf16x8 qf1 = *(const bf16x8*)(Q + qr * 64 + 32 + g * 8);

  f32x4 o = {0.f, 0.f, 0.f, 0.f};
  float M = -1e30f, Ls = 0.f;

  // loop-invariant bases
  const u16* Vrow = Vt + (size_t)qi * NL + g * 8;  // + t*64 (+32)
  const float* fbg = fbb + g * 4;                  // + t*64 (+ n*16)
  // K ds_read offsets (loop-invariant, swizzled)
  int koff[4][2];
#pragma unroll
  for (int n = 0; n < 4; ++n)
#pragma unroll
    for (int dc = 0; dc < 2; ++dc)
      koff[n][dc] = (((n * 16 + qi) * 128 + dc * 64 + g * 16) ^ swq);

  // ---- prologue: stage K tile 0 (wave-uniform LDS dst; swizzle in source) ----
#pragma unroll
  for (int i = 0; i < 2; ++i) {
    int off = wave * 2048 + i * 1024 + lane * 16;
    int src = off ^ ((off >> 3) & 0x70);
    __builtin_amdgcn_global_load_lds(AS1((const char*)K + src),
                                     AS3(lds + wave * 2048 + i * 1024), 16, 0, 0);
  }

  int cur = 0;
  for (int t = 0; t < 32; ++t) {
    __syncthreads();  // K buf[cur] ready (vmcnt drained before barrier)
    // issue K(t+1) stage into the other buffer
    if (t < 31) {
      const char* Kg = (const char*)(K + (size_t)(t + 1) * 4096);
      char* Kn = lds + (cur ^ 1) * 8192;
#pragma unroll
      for (int i = 0; i < 2; ++i) {
        int off = wave * 2048 + i * 1024 + lane * 16;
        int src = off ^ ((off >> 3) & 0x70);
        __builtin_amdgcn_global_load_lds(AS1(Kg + src),
                                         AS3(Kn + wave * 2048 + i * 1024), 16, 0, 0);
      }
    }
    const char* Kcur = lds + cur * 8192;

    // direct loads: bias (4x f32x4) and V (2x bf16x8, sigma-order)
    const float* fbt = fbg + t * 64;
    f32x4 fb0 = *(const f32x4*)(fbt);
    f32x4 fb1 = *(const f32x4*)(fbt + 16);
    f32x4 fb2 = *(const f32x4*)(fbt + 32);
    f32x4 fb3 = *(const f32x4*)(fbt + 48);
    const u16* Vtt = Vrow + t * 64;
    bf16x8 vf0 = *(const bf16x8*)(Vtt);
    bf16x8 vf1 = *(const bf16x8*)(Vtt + 32);

    // ---- QK^T (swapped): s_n[r] = S[key=16n+4g+r][q=qi]; bias rides C-in ----
    f32x4 s0, s1, s2, s3;
#define QK(n, dst, fbv)                                                    \
  {                                                                        \
    bf16x8 k0 = *(const bf16x8*)(Kcur + koff[n][0]);                       \
    bf16x8 k1 = *(const bf16x8*)(Kcur + koff[n][1]);                       \
    f32x4 z = __builtin_amdgcn_mfma_f32_16x16x32_bf16(k0, qf0, fbv, 0, 0, 0); \
    dst = __builtin_amdgcn_mfma_f32_16x16x32_bf16(k1, qf1, z, 0, 0, 0);    \
  }
    QK(0, s0, fb0) QK(1, s1, fb1) QK(2, s2, fb2) QK(3, s3, fb3)
#undef QK

    // ---- row max (16 in-lane + xor16/32) ----
    float m0 = fmaxf(fmaxf(s0[0], s0[1]), fmaxf(s0[2], s0[3]));
    float m1 = fmaxf(fmaxf(s1[0], s1[1]), fmaxf(s1[2], s1[3]));
    float m2 = fmaxf(fmaxf(s2[0], s2[1]), fmaxf(s2[2], s2[3]));
    float m3 = fmaxf(fmaxf(s3[0], s3[1]), fmaxf(s3[2], s3[3]));
    float mt = fmaxf(fmaxf(m0, m1), fmaxf(m2, m3));
    mt = fmaxf(mt, __shfl_xor(mt, 16));
    mt = fmaxf(mt, __shfl_xor(mt, 32));

    // ---- defer-rescale (T13, exp2 domain, THR=8) ----
    if (__any(mt > M + 8.f)) {
      float Mn = fmaxf(M, mt);
      float e = __builtin_amdgcn_exp2f(M - Mn);
      M = Mn;
      Ls *= e;
#pragma unroll
      for (int i = 0; i < 4; ++i) o[i] *= __shfl(e, g * 4 + i);
    }

    // ---- p = exp2(s-M) (native); pack via compiler cvt_pk; sum unrounded ----
    float p00 = __builtin_amdgcn_exp2f(s0[0] - M), p01 = __builtin_amdgcn_exp2f(s0[1] - M);
    float p02 = __builtin_amdgcn_exp2f(s0[2] - M), p03 = __builtin_amdgcn_exp2f(s0[3] - M);
    float p10 = __builtin_amdgcn_exp2f(s1[0] - M), p11 = __builtin_amdgcn_exp2f(s1[1] - M);
    float p12 = __builtin_amdgcn_exp2f(s1[2] - M), p13 = __builtin_amdgcn_exp2f(s1[3] - M);
    float p20 = __builtin_amdgcn_exp2f(s2[0] - M), p21 = __builtin_amdgcn_exp2f(s2[1] - M);
    float p22 = __builtin_amdgcn_exp2f(s2[2] - M), p23 = __builtin_amdgcn_exp2f(s2[3] - M);
    float p30 = __builtin_amdgcn_exp2f(s3[0] - M), p31 = __builtin_amdgcn_exp2f(s3[1] - M);
    float p32 = __builtin_amdgcn_exp2f(s3[2] - M), p33 = __builtin_amdgcn_exp2f(s3[3] - M);
    float rs = (((p00 + p01) + (p02 + p03)) + ((p10 + p11) + (p12 + p13))) +
               (((p20 + p21) + (p22 + p23)) + ((p30 + p31) + (p32 + p33)));
    rs += __shfl_xor(rs, 16);
    rs += __shfl_xor(rs, 32);
    Ls += rs;

    // PV A-frags directly from registers (sigma order):
    // pf0 = keys{n=0}(slots 0..3) + keys{n=2}(slots 4..7); pf1 = {n=1} + {n=3}
    bf16x8 pf0, pf1;
    pf0[0] = (__bf16)p00; pf0[1] = (__bf16)p01; pf0[2] = (__bf16)p02; pf0[3] = (__bf16)p03;
    pf0[4] = (__bf16)p20; pf0[5] = (__bf16)p21; pf0[6] = (__bf16)p22; pf0[7] = (__bf16)p23;
    pf1[0] = (__bf16)p10; pf1[1] = (__bf16)p11; pf1[2] = (__bf16)p12; pf1[3] = (__bf16)p13;
    pf1[4] = (__bf16)p30; pf1[5] = (__bf16)p31; pf1[6] = (__bf16)p32; pf1[7] = (__bf16)p33;

    // ---- PV ----
    o = __builtin_amdgcn_mfma_f32_16x16x32_bf16(pf0, vf0, o, 0, 0, 0);
    o = __builtin_amdgcn_mfma_f32_16x16x32_bf16(pf1, vf1, o, 0, 0, 0);
    cur ^= 1;
  }

  // ---- epilogue ----
  const size_t qrow0 = bh * NL + (size_t)qtile * 64 + wave * 16;
#pragma unroll
  for (int i = 0; i < 4; ++i) {
    float Li = __shfl(Ls, g * 4 + i);
    Oattn[(qrow0 + g * 4 + i) * NRH + qi] = o[i] / Li;
  }
}

// ---------------- final projection ----------------
__global__ void k_proj(const float* __restrict__ Oattn, const float* __restrict__ V,
                       float* __restrict__ out) {
  int bl = blockIdx.x;  // B*L
  int b = bl >> 11, l = bl & 2047;
  __shared__ float sO[256];
  int tid = threadIdx.x;
  sO[tid] = Oattn[((size_t)(b * NH + (tid >> 4)) * NL + l) * NRH + (tid & 15)];
  __syncthreads();
#pragma unroll
  for (int p = 0; p < 4; ++p) {
    int h = (tid >> 6) + p * 4;
    int d = tid & 63;
    float acc = 0.f;
    const float* Vh = V + (size_t)(h * NRH) * NHD + d;
    const float* Oh = sO + h * NRH;
#pragma unroll
    for (int r = 0; r < 16; ++r) acc += Oh[r] * Vh[(size_t)r * NHD];
    out[(size_t)bl * NDM + h * NHD + d] = acc;
  }
}

extern "C" void kernel_launch(void* const* d_in, const int* in_sizes, int n_in,
                              void* d_out, int out_size, void* d_ws, size_t ws_size,
                              hipStream_t stream) {
  (void)in_sizes; (void)n_in; (void)out_size; (void)ws_size;
  const float* x  = (const float*)d_in[0];
  const float* Wq = (const float*)d_in[1];
  const float* Wk = (const float*)d_in[2];
  const float* Wv = (const float*)d_in[3];
  const float* U  = (const float*)d_in[4];
  const float* Vm = (const float*)d_in[5];
  const int* mask = (const int*)d_in[6];
  float* out = (float*)d_out;
  char* ws = (char*)d_ws;

  u16* Wall   = (u16*)(ws);               // 4,718,592 B
  u16* xb     = (u16*)(ws + 4718592);     // 8,388,608 B (dead after GEMM)
  u16* pre    = (u16*)(ws + 13107200);    // 18,874,368 B
  u16* qt     = (u16*)(ws + 31981568);    // 8,388,608 B
  u16* ktb    = (u16*)(ws + 40370176);    // 8,388,608 B
  u16* vT     = (u16*)(ws + 48758784);    // 2,097,152 B
  float* ctab = (float*)(ws + 50855936);  // 262,144 B
  float* stab = (float*)(ws + 51118080);  // 262,144 B
  float* Oattn = (float*)(ws + 4718592);  // reuse xb region: 4 MB
  float* fbias = (float*)(ws + 8912896);  // reuse xb region tail: 16 KB

  k_prep_weff<<<dim3(9216), dim3(256), 0, stream>>>(Wq, Wk, Wv, U, Wall);
  k_cast_x<<<dim3(8192), dim3(256), 0, stream>>>(x, xb);
  k_rope_tab<<<dim3(256), dim3(256), 0, stream>>>(ctab, stab);
  k_gemm<<<dim3(32, 18), dim3(256), 0, stream>>>(xb, Wall, pre);
  k_fbias<<<dim3(16), dim3(256), 0, stream>>>(mask, fbias);
  k_rope<<<dim3(8192), dim3(256), 0, stream>>>(pre, ctab, stab, qt, ktb);
  k_vt<<<dim3(1024), dim3(256), 0, stream>>>(pre, vT);
  k_attn<<<dim3(1024), dim3(256), 0, stream>>>(qt, ktb, vT, fbias, Oattn);
  k_proj<<<dim3(4096), dim3(256), 0, stream>>>(Oattn, Vm, out);
}